// Round 2
// baseline (500.955 us; speedup 1.0000x reference)
//
#include <hip/hip_runtime.h>

// out[b,o] = sum_i W[i,o] * I[i,b],  I = per-object concat [first|mid0|mid1|last].
// ROWS = 17408 = 136 blocks of 128 rows; every 128-row block lies entirely in
// one source segment (offsets 0,128,4224,4352 all multiples of 128).
//
// Memory-bound: 285 MB of I streams once -> ~46 us floor at 6.3 TB/s.
// Round-1 lesson: per-row weight loads from global were NOT scalarized ->
// VMEM-issue-bound (~412 us). Fix: weights staged in LDS (broadcast ds_read),
// each wave owns 64 distinct b-columns, all 32 outputs per lane (acc in VGPRs).

#define BATCH  4096
#define OUTC   32
#define NCHUNK 34        // 34 chunks x 512 rows = 17408
#define BTILES 16        // 16 tiles x 256 b = 4096

// Block = 256 threads = 4 waves; block covers 256 consecutive b-columns and a
// 512-row chunk. Inner loop per row per wave: 1 coalesced global dword load
// (256 B), 8 broadcast ds_read_b128 (weights), 32 v_fma_f32 (64 cyc) ->
// VALU-dominated instruction mix, streams at up to 16 B/cyc/CU (9.8 TB/s chip).
__global__ __launch_bounds__(256) void cwl_partial(
    const float* __restrict__ cf,   // (4,128,4096)
    const float* __restrict__ cm,   // (4,2,2048,4096) == (4,4096,4096)
    const float* __restrict__ cl,   // (4,128,4096)
    const float* __restrict__ w,    // (17408,32)
    float* __restrict__ ws)         // (NCHUNK,4096,32) partials, [c][b][o]
{
    __shared__ float wlds[128 * OUTC];   // 16 KB: weights for one 128-row block

    const int chunk = blockIdx.x % NCHUNK;
    const int btile = blockIdx.x / NCHUNK;
    const int tid   = threadIdx.x;
    const int b     = btile * 256 + tid;

    float acc[OUTC];
#pragma unroll
    for (int j = 0; j < OUTC; ++j) acc[j] = 0.0f;

    for (int h = 0; h < 4; ++h) {
        const int m = chunk * 4 + h;          // global 128-row block, 0..135
        const int c = m / 34;                 // TT object
        const int j = m - c * 34;             // block within object, 0..33
        const float* src;
        if (j == 0)
            src = cf + (size_t)c * 128 * BATCH;
        else if (j == 33)
            src = cl + (size_t)c * 128 * BATCH;
        else
            src = cm + ((size_t)c * 4096 + (size_t)(j - 1) * 128) * BATCH;

        // Cooperative stage of 128 rows x 32 outs of weights (16 KB), float4.
        {
            const float4* wg = (const float4*)(w + (size_t)m * 128 * OUTC);
            float4* wl = (float4*)wlds;
#pragma unroll
            for (int k = 0; k < 4; ++k)
                wl[tid + 256 * k] = wg[tid + 256 * k];
        }
        __syncthreads();

        const float*  xp  = src + b;
        const float4* wl4 = (const float4*)wlds;
#pragma unroll 4
        for (int r = 0; r < 128; ++r) {
            const float x = xp[(size_t)r * BATCH];       // coalesced 256B/wave
            const float4* wr = wl4 + r * (OUTC / 4);     // wave-uniform addr
#pragma unroll
            for (int q = 0; q < OUTC / 4; ++q) {
                const float4 wv = wr[q];                 // LDS broadcast read
                acc[4*q+0] = fmaf(x, wv.x, acc[4*q+0]);
                acc[4*q+1] = fmaf(x, wv.y, acc[4*q+1]);
                acc[4*q+2] = fmaf(x, wv.z, acc[4*q+2]);
                acc[4*q+3] = fmaf(x, wv.w, acc[4*q+3]);
            }
        }
        __syncthreads();   // protect wlds before next stage overwrites it
    }

    // ws[chunk][b][o]: 32 contiguous floats per lane (8 dwordx4 stores).
    float4* dst = (float4*)(ws + ((size_t)chunk * BATCH + b) * OUTC);
#pragma unroll
    for (int q = 0; q < OUTC / 4; ++q)
        dst[q] = make_float4(acc[4*q+0], acc[4*q+1], acc[4*q+2], acc[4*q+3]);
}

// out[t] = sum_c ws[c][t], t = b*32+o. Reads and writes fully coalesced.
__global__ __launch_bounds__(256) void cwl_reduce(
    const float* __restrict__ ws, float* __restrict__ out)
{
    const int t = blockIdx.x * 256 + threadIdx.x;   // 0..131071
    float s = 0.0f;
#pragma unroll
    for (int c = 0; c < NCHUNK; ++c)
        s += ws[(size_t)c * (BATCH * OUTC) + t];
    out[t] = s;
}

extern "C" void kernel_launch(void* const* d_in, const int* in_sizes, int n_in,
                              void* d_out, int out_size, void* d_ws, size_t ws_size,
                              hipStream_t stream)
{
    const float* cf = (const float*)d_in[0];
    const float* cm = (const float*)d_in[1];
    const float* cl = (const float*)d_in[2];
    const float* w  = (const float*)d_in[3];
    float* out = (float*)d_out;
    float* ws  = (float*)d_ws;   // needs 34*131072*4 = 17.8 MB

    cwl_partial<<<dim3(NCHUNK * BTILES), dim3(256), 0, stream>>>(cf, cm, cl, w, ws);
    cwl_reduce<<<dim3((BATCH * OUTC) / 256), dim3(256), 0, stream>>>(ws, out);
}

// Round 3
// 467.749 us; speedup vs baseline: 1.0710x; 1.0710x over previous
//
#include <hip/hip_runtime.h>

// out[b,o] = sum_i W[i,o] * I[i,b],  I = per-object concat [first|mid0|mid1|last].
// ROWS = 17408 = 136 blocks of 128 rows; each 128-row block lies in one segment.
// Memory floor: 285 MB of I at 6.3 TB/s ~= 46 us.
//
// R2 lesson: (1) loads must be explicitly batched (register prefetch) or the
// compiler serializes them (1 outstanding load -> 14% VALU, 720 GB/s);
// (2) LDS broadcast ds_read_b128 cost is uncertain -> amortize each weight
// read over 4 b-columns x 4 outputs (64 FMAs per read).
// R2 discovery: harness ws poison fill = 1 GiB -> ws_size >= 1 GiB.

#define BATCH   4096
#define OUTC    32
#define NCHUNK  68      // chunks of 256 rows (2 x 128-row blocks); ws = 35.6 MB
#define BPC     2       // 128-row blocks per chunk
#define BTILES  8       // 8 b-tiles x 512 b

// Block = 256 thr = 4 waves. Wave (bsub,ohalf): bsub picks b range (0/256),
// ohalf picks outputs [0,16)/[16,32). Thread owns 4 consecutive b (float4
// loads, 1 KB/wave-instr) and 16 outputs -> acc = 64 VGPR.
__global__ __launch_bounds__(256) void cwl_partial(
    const float* __restrict__ cf,   // (4,128,4096)
    const float* __restrict__ cm,   // (4,2,2048,4096)
    const float* __restrict__ cl,   // (4,128,4096)
    const float* __restrict__ w,    // (17408,32)
    float* __restrict__ ws)         // (NCHUNK,4096,32)
{
    __shared__ float wlds[BPC * 128 * OUTC];   // 32 KB

    const int chunk = blockIdx.x % NCHUNK;
    const int btile = blockIdx.x / NCHUNK;
    const int tid   = threadIdx.x;
    const int wv    = tid >> 6;
    const int lane  = tid & 63;
    const int ohalf = wv & 1;
    const int bsub  = wv >> 1;
    const int b0    = btile * 512 + bsub * 256 + lane * 4;

    // Stage both 128-row weight blocks of this chunk (32 KB), one barrier.
    {
        float4* wl = (float4*)wlds;
#pragma unroll
        for (int h = 0; h < BPC; ++h) {
            const int m = chunk * BPC + h;
            const float4* wg = (const float4*)(w + (size_t)m * 128 * OUTC);
#pragma unroll
            for (int k = 0; k < 4; ++k)
                wl[h * 1024 + k * 256 + tid] = wg[k * 256 + tid];
        }
    }
    __syncthreads();

    float acc[16][4];
#pragma unroll
    for (int o = 0; o < 16; ++o)
#pragma unroll
        for (int bi = 0; bi < 4; ++bi) acc[o][bi] = 0.0f;

    for (int h = 0; h < BPC; ++h) {
        const int m = chunk * BPC + h;
        const int c = m / 34;
        const int j = m - c * 34;
        const float* src = (j == 0)  ? cf + (size_t)c * 128 * BATCH
                         : (j == 33) ? cl + (size_t)c * 128 * BATCH
                         : cm + ((size_t)c * 4096 + (size_t)(j - 1) * 128) * BATCH;
        const float4* xp  = (const float4*)src + (b0 >> 2);
        const float*  wlh = wlds + h * 128 * OUTC;

        for (int r0 = 0; r0 < 128; r0 += 4) {
            // Batched prefetch: 4 independent 1 KB loads in flight per wave.
            float4 x[4];
#pragma unroll
            for (int u = 0; u < 4; ++u)
                x[u] = xp[(size_t)(r0 + u) * (BATCH / 4)];
#pragma unroll
            for (int u = 0; u < 4; ++u) {
                const float4* wr = (const float4*)(wlh + (r0 + u) * OUTC + ohalf * 16);
#pragma unroll
                for (int q = 0; q < 4; ++q) {
                    const float4 wq = wr[q];   // wave-uniform LDS broadcast
#pragma unroll
                    for (int jj = 0; jj < 4; ++jj) {
                        const float wj = ((const float*)&wq)[jj];
                        const int o = q * 4 + jj;
                        acc[o][0] = fmaf(x[u].x, wj, acc[o][0]);
                        acc[o][1] = fmaf(x[u].y, wj, acc[o][1]);
                        acc[o][2] = fmaf(x[u].z, wj, acc[o][2]);
                        acc[o][3] = fmaf(x[u].w, wj, acc[o][3]);
                    }
                }
            }
        }
    }

    // ws[chunk][b][o]: each thread writes 16 floats for each of its 4 b's.
#pragma unroll
    for (int bi = 0; bi < 4; ++bi) {
        float4* dst = (float4*)(ws + ((size_t)chunk * BATCH + (b0 + bi)) * OUTC
                                + ohalf * 16);
#pragma unroll
        for (int q = 0; q < 4; ++q)
            dst[q] = make_float4(acc[q*4+0][bi], acc[q*4+1][bi],
                                 acc[q*4+2][bi], acc[q*4+3][bi]);
    }
}

// out[t] = sum_c ws[c][t]; fully coalesced.
__global__ __launch_bounds__(256) void cwl_reduce(
    const float* __restrict__ ws, float* __restrict__ out)
{
    const int t = blockIdx.x * 256 + threadIdx.x;   // 0..131071
    float s = 0.0f;
#pragma unroll
    for (int c = 0; c < NCHUNK; ++c)
        s += ws[(size_t)c * (BATCH * OUTC) + t];
    out[t] = s;
}

extern "C" void kernel_launch(void* const* d_in, const int* in_sizes, int n_in,
                              void* d_out, int out_size, void* d_ws, size_t ws_size,
                              hipStream_t stream)
{
    const float* cf = (const float*)d_in[0];
    const float* cm = (const float*)d_in[1];
    const float* cl = (const float*)d_in[2];
    const float* w  = (const float*)d_in[3];
    float* out = (float*)d_out;
    float* ws  = (float*)d_ws;   // needs 68*131072*4 = 35.6 MB (ws >= 1 GiB)

    cwl_partial<<<dim3(NCHUNK * BTILES), dim3(256), 0, stream>>>(cf, cm, cl, w, ws);
    cwl_reduce<<<dim3((BATCH * OUTC) / 256), dim3(256), 0, stream>>>(ws, out);
}

// Round 4
// 436.826 us; speedup vs baseline: 1.1468x; 1.0708x over previous
//
#include <hip/hip_runtime.h>

// out[b,o] = sum_i W[i,o] * I[i,b],  I = per-object concat [first|mid0|mid1|last].
// ROWS = 17408 = 136 blocks of 128 rows; each 128-row block lies in one segment.
// Memory floor: 285 MB of I at 6.3 TB/s ~= 46 us (+71 MB ws writes -> ~57 us).
//
// R3 lesson: 544 blocks = 8.5 waves/CU was the limiter (Occupancy 21%,
// VALUBusy 17%, 1.5 TB/s effective). This round: 1088 blocks = 17 waves/CU
// + explicit 2-stage pipeline (4 loads always in flight per wave).
// R2 discovery: harness poison of the 1 GiB ws + input restore ~= 270 us of
// dur_us is fixed overhead; kernel-side target is ~80 us combined.

#define BATCH   4096
#define OUTC    32
#define NCHUNK  136     // one 128-row block per chunk; ws = 71.3 MB (ws >= 1 GiB)
#define BTILES  8       // 8 b-tiles x 512 b

// Block = 256 thr = 4 waves = 2 bsub x 2 ohalf over a 512b x 128row tile.
// Thread: 4 consecutive b (float4 loads, 1 KB/wave-instr) x 16 outs -> 64 acc.
__global__ __launch_bounds__(256, 4) void cwl_partial(
    const float* __restrict__ cf,   // (4,128,4096)
    const float* __restrict__ cm,   // (4,2,2048,4096)
    const float* __restrict__ cl,   // (4,128,4096)
    const float* __restrict__ w,    // (17408,32)
    float* __restrict__ ws)         // (NCHUNK,4096,32)
{
    __shared__ float wlds[128 * OUTC];   // 16 KB

    const int chunk = blockIdx.x % NCHUNK;   // row-block 0..135
    const int btile = blockIdx.x / NCHUNK;
    const int tid   = threadIdx.x;
    const int wv    = tid >> 6;
    const int lane  = tid & 63;
    const int ohalf = wv & 1;
    const int bsub  = wv >> 1;
    const int b0    = btile * 512 + bsub * 256 + lane * 4;

    // Stage this block's 128x32 weights (16 KB), 4 float4 per thread.
    {
        const float4* wg = (const float4*)(w + (size_t)chunk * 128 * OUTC);
        float4* wl = (float4*)wlds;
#pragma unroll
        for (int k = 0; k < 4; ++k)
            wl[k * 256 + tid] = wg[k * 256 + tid];
    }

    const int c = chunk / 34;
    const int j = chunk % 34;
    const float* src = (j == 0)  ? cf + (size_t)c * 128 * BATCH
                     : (j == 33) ? cl + (size_t)c * 128 * BATCH
                     : cm + ((size_t)c * 4096 + (size_t)(j - 1) * 128) * BATCH;
    const float4* xp = (const float4*)src + (b0 >> 2);

    // Preload rows 0..3 before the barrier (overlap with weight staging).
    float4 xa[4], xb[4];
#pragma unroll
    for (int u = 0; u < 4; ++u)
        xa[u] = xp[(size_t)u * (BATCH / 4)];

    __syncthreads();

    float acc[16][4];
#pragma unroll
    for (int o = 0; o < 16; ++o)
#pragma unroll
        for (int bi = 0; bi < 4; ++bi) acc[o][bi] = 0.0f;

    const float* wlh = wlds + ohalf * 16;

#define CWL_COMPUTE(XREG, RBASE)                                          \
    do {                                                                  \
        _Pragma("unroll")                                                 \
        for (int u = 0; u < 4; ++u) {                                     \
            const float4* wr = (const float4*)(wlh + (RBASE + u) * OUTC); \
            _Pragma("unroll")                                             \
            for (int q = 0; q < 4; ++q) {                                 \
                const float4 wq = wr[q];   /* wave-uniform broadcast */   \
                _Pragma("unroll")                                         \
                for (int jj = 0; jj < 4; ++jj) {                          \
                    const float wj = ((const float*)&wq)[jj];             \
                    const int o = q * 4 + jj;                             \
                    acc[o][0] = fmaf(XREG[u].x, wj, acc[o][0]);           \
                    acc[o][1] = fmaf(XREG[u].y, wj, acc[o][1]);           \
                    acc[o][2] = fmaf(XREG[u].z, wj, acc[o][2]);           \
                    acc[o][3] = fmaf(XREG[u].w, wj, acc[o][3]);           \
                }                                                         \
            }                                                             \
        }                                                                 \
    } while (0)

    for (int r0 = 0; r0 < 128; r0 += 8) {
        // Issue next 4 loads before computing on the previous 4: vmcnt FIFO
        // keeps 4 loads in flight through every compute phase.
#pragma unroll
        for (int u = 0; u < 4; ++u)
            xb[u] = xp[(size_t)(r0 + 4 + u) * (BATCH / 4)];
        CWL_COMPUTE(xa, r0);
        const int rn = (r0 + 8 < 128) ? r0 + 8 : 124;  // clamp: no OOB prefetch
#pragma unroll
        for (int u = 0; u < 4; ++u)
            xa[u] = xp[(size_t)(rn + u) * (BATCH / 4)];
        CWL_COMPUTE(xb, r0 + 4);
    }

    // ws[chunk][b][o]: 16 floats per (thread, bi) -> coalesced float4 stores.
#pragma unroll
    for (int bi = 0; bi < 4; ++bi) {
        float4* dst = (float4*)(ws + ((size_t)chunk * BATCH + (b0 + bi)) * OUTC
                                + ohalf * 16);
#pragma unroll
        for (int q = 0; q < 4; ++q)
            dst[q] = make_float4(acc[q*4+0][bi], acc[q*4+1][bi],
                                 acc[q*4+2][bi], acc[q*4+3][bi]);
    }
}

// out[t] = sum_c ws[c][t]; 4 independent accumulators for load-level MLP.
__global__ __launch_bounds__(256) void cwl_reduce(
    const float* __restrict__ ws, float* __restrict__ out)
{
    const int t = blockIdx.x * 256 + threadIdx.x;   // 0..131071
    float s0 = 0.f, s1 = 0.f, s2 = 0.f, s3 = 0.f;
#pragma unroll 4
    for (int c = 0; c < NCHUNK; c += 4) {
        s0 += ws[(size_t)(c+0) * (BATCH * OUTC) + t];
        s1 += ws[(size_t)(c+1) * (BATCH * OUTC) + t];
        s2 += ws[(size_t)(c+2) * (BATCH * OUTC) + t];
        s3 += ws[(size_t)(c+3) * (BATCH * OUTC) + t];
    }
    out[t] = (s0 + s1) + (s2 + s3);
}

extern "C" void kernel_launch(void* const* d_in, const int* in_sizes, int n_in,
                              void* d_out, int out_size, void* d_ws, size_t ws_size,
                              hipStream_t stream)
{
    const float* cf = (const float*)d_in[0];
    const float* cm = (const float*)d_in[1];
    const float* cl = (const float*)d_in[2];
    const float* w  = (const float*)d_in[3];
    float* out = (float*)d_out;
    float* ws  = (float*)d_ws;   // 136*131072*4 = 71.3 MB used

    cwl_partial<<<dim3(NCHUNK * BTILES), dim3(256), 0, stream>>>(cf, cm, cl, w, ws);
    cwl_reduce<<<dim3((BATCH * OUTC) / 256), dim3(256), 0, stream>>>(ws, out);
}

// Round 5
// 406.496 us; speedup vs baseline: 1.2324x; 1.0746x over previous
//
#include <hip/hip_runtime.h>
#include <stdint.h>

// out[b,o] = sum_i W[i,o] * I[i,b],  I = per-object concat [first|mid0|mid1|last].
// ROWS = 17408 = 136 blocks of 128 rows; each 128-row block lies in one segment.
//
// R4 lesson: the VGPR global-load path is stuck at ~1 outstanding load/wave
// (compiler waitcnt), BW scales only with wave count -> 1.75 TB/s ceiling at
// ~10 waves/CU. This round: x streams via global_load_lds DMA (register-free
// in-flight bytes, m97-proven), double-buffered 8-row stages in LDS.
// Fixed harness overhead (1 GiB ws poison + input restore) ~= 260 us of dur_us.

#define BATCH  4096
#define OUTC   32
#define NCHUNK 136     // one 128-row block per chunk; ws = 71.3 MB
#define BTILES 8       // 8 b-tiles x 512 b
#define RSTAGE 8       // rows per pipeline stage (16 KB / stage)
#define NSTAGE 16      // 128 / RSTAGE

// DMA one 16B/lane wave-copy: 64 lanes * 16 B = 1024 B contiguous into LDS at
// a wave-uniform base (global_load_lds semantics: dst = base + lane*16).
__device__ __forceinline__ void dma16(const float* g, float* l) {
    __builtin_amdgcn_global_load_lds(
        (const __attribute__((address_space(1))) void*)g,
        (__attribute__((address_space(3))) void*)l, 16, 0, 0);
}

// Block = 256 thr = 4 waves (bsub x ohalf) over a 512b x 128row tile.
// Thread: 4 consecutive b x 16 outs -> 64 accumulators.
__global__ __launch_bounds__(256, 3) void cwl_partial(
    const float* __restrict__ cf,   // (4,128,4096)
    const float* __restrict__ cm,   // (4,2,2048,4096)
    const float* __restrict__ cl,   // (4,128,4096)
    const float* __restrict__ w,    // (17408,32)
    float* __restrict__ ws)         // (NCHUNK,4096,32)
{
    __shared__ float wlds[128 * OUTC];          // 16 KB: this block's weights
    __shared__ float xlds[2][RSTAGE * 512];     // 2 x 16 KB: x double-buffer

    const int chunk = blockIdx.x % NCHUNK;      // row-block 0..135
    const int btile = blockIdx.x / NCHUNK;
    const int tid   = threadIdx.x;
    const int wv    = tid >> 6;
    const int lane  = tid & 63;
    const int ohalf = wv & 1;
    const int bsub  = wv >> 1;

    const int c = chunk / 34;
    const int j = chunk % 34;
    const float* src = (j == 0)  ? cf + (size_t)c * 128 * BATCH
                     : (j == 33) ? cl + (size_t)c * 128 * BATCH
                     : cm + ((size_t)c * 4096 + (size_t)(j - 1) * 128) * BATCH;
    const float* srcg = src + btile * 512;                  // block's b-slice
    const float* wg   = w + (size_t)chunk * 128 * OUTC;     // 4096 floats

    // Stage weights (16 wave-copies) + x stage 0 (16 wave-copies), one barrier.
#pragma unroll
    for (int t = 0; t < 4; ++t) {
        const int seg = wv * 4 + t;                          // 0..15
        dma16(wg + seg * 256 + lane * 4, wlds + seg * 256);
    }
#pragma unroll
    for (int t = 0; t < 4; ++t) {
        const int row  = wv * 2 + (t >> 1);                  // 0..7
        const int half = t & 1;
        dma16(srcg + (size_t)row * BATCH + half * 256 + lane * 4,
              &xlds[0][row * 512 + half * 256]);
    }
    __syncthreads();

    float acc[16][4];
#pragma unroll
    for (int o = 0; o < 16; ++o)
#pragma unroll
        for (int bi = 0; bi < 4; ++bi) acc[o][bi] = 0.0f;

    const int xoff = bsub * 256 + lane * 4;   // thread's float4 within a row

    for (int s = 0; s < NSTAGE; ++s) {
        // Issue DMA for stage s+1 into the other buffer, then compute stage s.
        if (s + 1 < NSTAGE) {
            float* xn = xlds[(s + 1) & 1];
            const int r0 = (s + 1) * RSTAGE;
#pragma unroll
            for (int t = 0; t < 4; ++t) {
                const int row  = wv * 2 + (t >> 1);
                const int half = t & 1;
                dma16(srcg + (size_t)(r0 + row) * BATCH + half * 256 + lane * 4,
                      xn + row * 512 + half * 256);
            }
        }
        const float* xb   = xlds[s & 1];
        const float* wrow = wlds + s * RSTAGE * OUTC + ohalf * 16;
#pragma unroll
        for (int r = 0; r < RSTAGE; ++r) {
            const float4 x = *(const float4*)(xb + r * 512 + xoff);
            const float4* wr = (const float4*)(wrow + r * OUTC);
#pragma unroll
            for (int q = 0; q < 4; ++q) {
                const float4 wq = wr[q];     // wave-uniform LDS broadcast
#pragma unroll
                for (int jj = 0; jj < 4; ++jj) {
                    const float wj = ((const float*)&wq)[jj];
                    const int o = q * 4 + jj;
                    acc[o][0] = fmaf(x.x, wj, acc[o][0]);
                    acc[o][1] = fmaf(x.y, wj, acc[o][1]);
                    acc[o][2] = fmaf(x.z, wj, acc[o][2]);
                    acc[o][3] = fmaf(x.w, wj, acc[o][3]);
                }
            }
        }
        __syncthreads();   // drains s+1 DMA; protects xb for stage s+2 reuse
    }

    // ws[chunk][b][o]: 16 floats per (thread, bi) -> coalesced float4 stores.
    const int b0 = btile * 512 + bsub * 256 + lane * 4;
#pragma unroll
    for (int bi = 0; bi < 4; ++bi) {
        float4* dst = (float4*)(ws + ((size_t)chunk * BATCH + (b0 + bi)) * OUTC
                                + ohalf * 16);
#pragma unroll
        for (int q = 0; q < 4; ++q)
            dst[q] = make_float4(acc[q*4+0][bi], acc[q*4+1][bi],
                                 acc[q*4+2][bi], acc[q*4+3][bi]);
    }
}

// out[t] = sum_c ws[c][t]; 4 independent chains, fully coalesced.
__global__ __launch_bounds__(256) void cwl_reduce(
    const float* __restrict__ ws, float* __restrict__ out)
{
    const int t = blockIdx.x * 256 + threadIdx.x;   // 0..131071
    float s0 = 0.f, s1 = 0.f, s2 = 0.f, s3 = 0.f;
#pragma unroll 4
    for (int c = 0; c < NCHUNK; c += 4) {
        s0 += ws[(size_t)(c+0) * (BATCH * OUTC) + t];
        s1 += ws[(size_t)(c+1) * (BATCH * OUTC) + t];
        s2 += ws[(size_t)(c+2) * (BATCH * OUTC) + t];
        s3 += ws[(size_t)(c+3) * (BATCH * OUTC) + t];
    }
    out[t] = (s0 + s1) + (s2 + s3);
}

extern "C" void kernel_launch(void* const* d_in, const int* in_sizes, int n_in,
                              void* d_out, int out_size, void* d_ws, size_t ws_size,
                              hipStream_t stream)
{
    const float* cf = (const float*)d_in[0];
    const float* cm = (const float*)d_in[1];
    const float* cl = (const float*)d_in[2];
    const float* w  = (const float*)d_in[3];
    float* out = (float*)d_out;
    float* ws  = (float*)d_ws;   // 136*131072*4 = 71.3 MB used

    cwl_partial<<<dim3(NCHUNK * BTILES), dim3(256), 0, stream>>>(cf, cm, cl, w, ws);
    cwl_reduce<<<dim3((BATCH * OUTC) / 256), dim3(256), 0, stream>>>(ws, out);
}